// Round 3
// baseline (400.642 us; speedup 1.0000x reference)
//
#include <hip/hip_runtime.h>

// x (64, 16, 16, 1024) fp32 -> cov (64, 1024, 1024) fp32
// cov[n] = (S - su su^T/256)/255 + 1e-5*I,  S = sum_s x[n,s,:] x[n,s,:]^T
#define EPSV 1e-5f

typedef __attribute__((ext_vector_type(8))) short s16x8;   // 8 bf16 = 4 VGPR (MFMA A/B frag)
typedef __attribute__((ext_vector_type(4))) float f32x4;   // MFMA C/D frag

__device__ __forceinline__ unsigned short f2bf(float f) {  // RN-even fp32->bf16
  unsigned int u = __float_as_uint(f);
  u += 0x7fff + ((u >> 16) & 1);
  return (unsigned short)(u >> 16);
}
__device__ __forceinline__ float bf2f(unsigned short h) {
  return __uint_as_float(((unsigned int)h) << 16);
}

// ---------------- kernel 1: transpose + hi/lo split + swizzle-pack + partial sums ----
// Packed layout: tile(n, fb in 8, kb in 8, half in {hi,lo}) of 8192 B.
// Element (f_local in 128, k_local in 32) at byte:
//   f_local*64 + ((k_local>>3) ^ ((f_local>>1)&3))*16 + (k_local&7)*2
// This IS the LDS image: GEMM stages with linear 16B global_load_lds; fragment
// ds_read_b128 lands 2-way bank aliased (free, m136).
__global__ __launch_bounds__(256) void pack_kernel(const float* __restrict__ x,
                                                   unsigned char* __restrict__ pk,
                                                   float* __restrict__ psum) {
  __shared__ float tile[64][129];  // 64 s-rows x 128 f, +1 pad
  const int b = blockIdx.x;        // 2048 = 64 n * 8 fb * 4 sb
  const int n = b >> 5, fb = (b >> 2) & 7, sb = b & 3;
  const int t = threadIdx.x;
  const float* src = x + ((size_t)(n * 256 + sb * 64)) * 1024 + fb * 128;

  // phase 1: coalesced float4 reads, [s][f] into LDS
  const int f4 = (t & 31) * 4;
  const int srow = t >> 5;
#pragma unroll
  for (int r = 0; r < 8; ++r) {
    const int s = r * 8 + srow;
    const float4 v = *reinterpret_cast<const float4*>(src + (size_t)s * 1024 + f4);
    tile[s][f4 + 0] = v.x;
    tile[s][f4 + 1] = v.y;
    tile[s][f4 + 2] = v.z;
    tile[s][f4 + 3] = v.w;
  }
  __syncthreads();

  // phase 2: thread owns (f, 8-s chunk); convert, split, 16B coalesced stores;
  // partial column sums octet-reduced via shfl_xor.
  const int sc = t & 7;                 // s-chunk within the 64-s block
  const int chunk = sc & 3;
  const int kb0 = sb * 2 + (sc >> 2);
#pragma unroll
  for (int r = 0; r < 4; ++r) {
    const int f = (t >> 3) + r * 32;
    s16x8 hi, lo;
    float ps = 0.f;
#pragma unroll
    for (int i = 0; i < 8; ++i) {
      const float v = tile[sc * 8 + i][f];
      ps += v;
      const unsigned short h = f2bf(v);
      hi[i] = (short)h;
      lo[i] = (short)f2bf(v - bf2f(h));
    }
    const int pos = chunk ^ ((f >> 1) & 3);
    const size_t tb = ((size_t)(((n * 8 + fb) * 8 + kb0) * 2)) * 8192 +
                      (size_t)(f * 64 + pos * 16);
    *reinterpret_cast<s16x8*>(pk + tb) = hi;
    *reinterpret_cast<s16x8*>(pk + tb + 8192) = lo;
    ps += __shfl_xor(ps, 1);
    ps += __shfl_xor(ps, 2);
    ps += __shfl_xor(ps, 4);
    if (sc == 0) psum[(size_t)(n * 4 + sb) * 1024 + fb * 128 + f] = ps;
  }
}

// ---------------- kernel 2: triangular batched SYRK, 2-phase counted-wait ----------
typedef const __attribute__((address_space(1))) void* gas_t;
typedef __attribute__((address_space(3))) void* las_t;
__device__ __forceinline__ void gload16(const unsigned char* g, unsigned char* l) {
  __builtin_amdgcn_global_load_lds((gas_t)g, (las_t)l, 16, 0, 0);
}
#define WAITV0() asm volatile("s_waitcnt vmcnt(0)" ::: "memory")
#define BAR() asm volatile("s_barrier" ::: "memory")

__global__ __launch_bounds__(256, 2) void cov_gemm(const unsigned char* __restrict__ pk,
                                                   const float* __restrict__ psum,
                                                   float* __restrict__ out) {
  // XCD-aware: each XCD owns whole batches (per-batch pk = 1MB << 4MB L2);
  // 36 consecutive blocks per XCD share one batch -> L2-resident reuse.
  const int raw = blockIdx.x;          // 2304 = 36 tile-pairs * 64 batches
  const int xcd = raw & 7;
  const int i = raw >> 3;
  const int n = (i / 36) * 8 + xcd;
  int tp = i % 36;
  int bi = 0;
  while (tp >= 8 - bi) { tp -= 8 - bi; ++bi; }
  const int bj = bi + tp;

  const int t = threadIdx.x;
  const int lane = t & 63;
  const int w = t >> 6;                // 4 waves, 2x2 over the 128x128 tile
  const int wm = w >> 1, wn = w & 1;
  const int fr = lane & 15, g = lane >> 4;

  __shared__ __align__(16) unsigned char lds[2][4][8192];  // dbuf x {Ahi,Alo,Bhi,Blo}

  f32x4 acc[4][4];
#pragma unroll
  for (int a = 0; a < 4; ++a)
#pragma unroll
    for (int c = 0; c < 4; ++c) acc[a][c] = (f32x4){0.f, 0.f, 0.f, 0.f};

  const size_t baseA = (size_t)((n * 8 + bi) * 8) * 2 * 8192;
  const size_t baseB = (size_t)((n * 8 + bj) * 8) * 2 * 8192;
  const int o = t * 16;

  // fragment LDS byte offsets (same swizzle as pack layout; A/B patterns
  // identical so any k-slot permutation cancels between operands)
  int offA[4], offB[4];
#pragma unroll
  for (int mi = 0; mi < 4; ++mi) {
    const int fa = wm * 64 + mi * 16 + fr;
    offA[mi] = fa * 64 + ((g ^ ((fa >> 1) & 3)) * 16);
    const int fbc = wn * 64 + mi * 16 + fr;
    offB[mi] = fbc * 64 + ((g ^ ((fbc >> 1) & 3)) * 16);
  }

#define STAGE(buf, kb)                                                     \
  do {                                                                     \
    const unsigned char* pA = pk + baseA + (size_t)(kb)*16384;             \
    const unsigned char* pB = pk + baseB + (size_t)(kb)*16384;             \
    gload16(pA + o,         &lds[buf][0][o]);                              \
    gload16(pA + o + 4096,  &lds[buf][0][o + 4096]);                       \
    gload16(pA + 8192 + o,  &lds[buf][1][o]);                              \
    gload16(pA + 12288 + o, &lds[buf][1][o + 4096]);                       \
    gload16(pB + o,         &lds[buf][2][o]);                              \
    gload16(pB + o + 4096,  &lds[buf][2][o + 4096]);                       \
    gload16(pB + 8192 + o,  &lds[buf][3][o]);                              \
    gload16(pB + 12288 + o, &lds[buf][3][o + 4096]);                       \
  } while (0)

  STAGE(0, 0);
  WAITV0();  // own loads landed; barrier aligns all waves -> buf0 globally ready
  BAR();

  for (int kb = 0; kb < 8; ++kb) {
    const int cur = kb & 1;
    // prefetch next tile into the other buffer; its loads fly under this
    // iteration's MFMA block. buf[cur^1] was last read in iter kb-1 and the
    // end-of-iter barrier ordered those reads before this overwrite.
    if (kb < 7) STAGE(cur ^ 1, kb + 1);

    s16x8 ah[4], al[4], bh[4], bl[4];
#pragma unroll
    for (int mi = 0; mi < 4; ++mi) {
      ah[mi] = *reinterpret_cast<const s16x8*>(&lds[cur][0][offA[mi]]);
      al[mi] = *reinterpret_cast<const s16x8*>(&lds[cur][1][offA[mi]]);
    }
#pragma unroll
    for (int nj = 0; nj < 4; ++nj) {
      bh[nj] = *reinterpret_cast<const s16x8*>(&lds[cur][2][offB[nj]]);
      bl[nj] = *reinterpret_cast<const s16x8*>(&lds[cur][3][offB[nj]]);
    }
#pragma unroll
    for (int mi = 0; mi < 4; ++mi)
#pragma unroll
      for (int nj = 0; nj < 4; ++nj) {
        // S ~= hi*hi + hi*lo + lo*hi  (drop lo*lo: ~2^-16 rel)
        acc[mi][nj] = __builtin_amdgcn_mfma_f32_16x16x32_bf16(ah[mi], bh[nj], acc[mi][nj], 0, 0, 0);
        acc[mi][nj] = __builtin_amdgcn_mfma_f32_16x16x32_bf16(ah[mi], bl[nj], acc[mi][nj], 0, 0, 0);
        acc[mi][nj] = __builtin_amdgcn_mfma_f32_16x16x32_bf16(al[mi], bh[nj], acc[mi][nj], 0, 0, 0);
      }

    if (kb < 7) {
      WAITV0();  // tile kb+1 loads (issued above, covered by MFMA) complete
      BAR();     // + all waves done reading buf[cur] -> safe to overwrite next iter
    }
  }
#undef STAGE

  // epilogue: mean correction (su from psum partials, L2-hit) + eps*I; mirror
  const float* pn = psum + (size_t)n * 4096;
  float sd[4];
#pragma unroll
  for (int nj = 0; nj < 4; ++nj) {
    const int c = bj * 128 + wn * 64 + nj * 16 + fr;
    sd[nj] = pn[c] + pn[1024 + c] + pn[2048 + c] + pn[3072 + c];
  }
  float sr_[4][4];
#pragma unroll
  for (int mi = 0; mi < 4; ++mi)
#pragma unroll
    for (int j = 0; j < 4; ++j) {
      const int r = bi * 128 + wm * 64 + mi * 16 + g * 4 + j;
      sr_[mi][j] = pn[r] + pn[1024 + r] + pn[2048 + r] + pn[3072 + r];
    }

  float* outn = out + (size_t)n * (1024 * 1024);
  const bool mir = (bi != bj);
#pragma unroll
  for (int mi = 0; mi < 4; ++mi) {
    const int rbase = bi * 128 + wm * 64 + mi * 16 + g * 4;
#pragma unroll
    for (int nj = 0; nj < 4; ++nj) {
      const int d = bj * 128 + wn * 64 + nj * 16 + fr;
#pragma unroll
      for (int j = 0; j < 4; ++j) {
        const int r = rbase + j;
        // C/D mapping (m89): col = lane&15, row = (lane>>4)*4 + j
        float v = (acc[mi][nj][j] - sr_[mi][j] * sd[nj] * (1.f / 256.f)) * (1.f / 255.f);
        if (r == d) v += EPSV;
        outn[(size_t)r * 1024 + d] = v;
        if (mir) outn[(size_t)d * 1024 + r] = v;
      }
    }
  }
}

// ---------------- fallback (workspace too small): direct fp32 ----------------
__global__ __launch_bounds__(256) void cov_naive(const float* __restrict__ x,
                                                 float* __restrict__ out) {
  const size_t idx = (size_t)blockIdx.x * 256 + threadIdx.x;
  const int d = (int)(idx & 1023);
  const int c = (int)((idx >> 10) & 1023);
  const int n = (int)(idx >> 20);
  const float* xp = x + (size_t)n * (256 * 1024);
  float scd = 0.f, sc = 0.f, sdd = 0.f;
  for (int s = 0; s < 256; ++s) {
    const float a = xp[(size_t)s * 1024 + c];
    const float bq = xp[(size_t)s * 1024 + d];
    scd += a * bq;
    sc += a;
    sdd += bq;
  }
  float v = (scd - sc * sdd * (1.f / 256.f)) * (1.f / 255.f);
  if (c == d) v += EPSV;
  out[idx] = v;
}

extern "C" void kernel_launch(void* const* d_in, const int* in_sizes, int n_in,
                              void* d_out, int out_size, void* d_ws, size_t ws_size,
                              hipStream_t stream) {
  const float* x = (const float*)d_in[0];
  float* out = (float*)d_out;
  const size_t PK_BYTES = (size_t)64 * 8 * 8 * 2 * 8192;  // 67,108,864
  const size_t PSUM_BYTES = (size_t)64 * 4 * 1024 * 4;    // 1 MB
  if (ws_size >= PK_BYTES + PSUM_BYTES) {
    unsigned char* pk = (unsigned char*)d_ws;
    float* psum = (float*)((unsigned char*)d_ws + PK_BYTES);
    hipLaunchKernelGGL(pack_kernel, dim3(2048), dim3(256), 0, stream, x, pk, psum);
    hipLaunchKernelGGL(cov_gemm, dim3(2304), dim3(256), 0, stream, pk, psum, out);
  } else {
    hipLaunchKernelGGL(cov_naive, dim3(262144), dim3(256), 0, stream, x, out);
  }
}

// Round 5
// 341.927 us; speedup vs baseline: 1.1717x; 1.1717x over previous
//
#include <hip/hip_runtime.h>

// x (64, 16, 16, 1024) fp32 -> cov (64, 1024, 1024) fp32
// cov[n] = (S - su su^T/256)/255 + 1e-5*I,  S = sum_s x[n,s,:] x[n,s,:]^T
#define EPSV 1e-5f

typedef __attribute__((ext_vector_type(8))) short s16x8;   // 8 bf16 = 4 VGPR (MFMA A/B frag)
typedef __attribute__((ext_vector_type(4))) float f32x4;   // MFMA C/D frag

__device__ __forceinline__ unsigned short f2bf(float f) {  // RN-even fp32->bf16
  unsigned int u = __float_as_uint(f);
  u += 0x7fff + ((u >> 16) & 1);
  return (unsigned short)(u >> 16);
}
__device__ __forceinline__ float bf2f(unsigned short h) {
  return __uint_as_float(((unsigned int)h) << 16);
}

// ---------------- kernel 1: transpose + hi/lo split + swizzle-pack + partial sums ----
// Packed layout: tile(n, fb in 8, kb in 8, half in {hi,lo}) of 8192 B.
// Element (f_local in 128, k_local in 32) at byte:
//   f_local*64 + ((k_local>>3) ^ ((f_local>>1)&3))*16 + (k_local&7)*2
// This IS the LDS image: GEMM stages with linear 16B global_load_lds; fragment
// ds_read_b128 lands 2-way bank aliased (free, m136).
__global__ __launch_bounds__(256) void pack_kernel(const float* __restrict__ x,
                                                   unsigned char* __restrict__ pk,
                                                   float* __restrict__ psum) {
  __shared__ float tile[64][129];  // 64 s-rows x 128 f, +1 pad
  const int b = blockIdx.x;        // 2048 = 64 n * 8 fb * 4 sb
  const int n = b >> 5, fb = (b >> 2) & 7, sb = b & 3;
  const int t = threadIdx.x;
  const float* src = x + ((size_t)(n * 256 + sb * 64)) * 1024 + fb * 128;

  // phase 1: coalesced float4 reads (nontemporal: x has a single reader)
  const int f4 = (t & 31) * 4;
  const int srow = t >> 5;
#pragma unroll
  for (int r = 0; r < 8; ++r) {
    const int s = r * 8 + srow;
    const f32x4 v = __builtin_nontemporal_load(
        reinterpret_cast<const f32x4*>(src + (size_t)s * 1024 + f4));
    tile[s][f4 + 0] = v[0];
    tile[s][f4 + 1] = v[1];
    tile[s][f4 + 2] = v[2];
    tile[s][f4 + 3] = v[3];
  }
  __syncthreads();

  // phase 2: thread owns (f, 8-s chunk); convert, split, 16B coalesced stores;
  // partial column sums octet-reduced via shfl_xor.
  const int sc = t & 7;                 // s-chunk within the 64-s block
  const int chunk = sc & 3;
  const int kb0 = sb * 2 + (sc >> 2);
#pragma unroll
  for (int r = 0; r < 4; ++r) {
    const int f = (t >> 3) + r * 32;
    s16x8 hi, lo;
    float ps = 0.f;
#pragma unroll
    for (int i = 0; i < 8; ++i) {
      const float v = tile[sc * 8 + i][f];
      ps += v;
      const unsigned short h = f2bf(v);
      hi[i] = (short)h;
      lo[i] = (short)f2bf(v - bf2f(h));
    }
    const int pos = chunk ^ ((f >> 1) & 3);
    const size_t tb = ((size_t)(((n * 8 + fb) * 8 + kb0) * 2)) * 8192 +
                      (size_t)(f * 64 + pos * 16);
    *reinterpret_cast<s16x8*>(pk + tb) = hi;
    *reinterpret_cast<s16x8*>(pk + tb + 8192) = lo;
    ps += __shfl_xor(ps, 1);
    ps += __shfl_xor(ps, 2);
    ps += __shfl_xor(ps, 4);
    if (sc == 0) psum[(size_t)(n * 4 + sb) * 1024 + fb * 128 + f] = ps;
  }
}

// ---------------- kernel 2: triangular batched SYRK, 2-phase + LDS-transposed mirror -
typedef const __attribute__((address_space(1))) void* gas_t;
typedef __attribute__((address_space(3))) void* las_t;
__device__ __forceinline__ void gload16(const unsigned char* g, unsigned char* l) {
  __builtin_amdgcn_global_load_lds((gas_t)g, (las_t)l, 16, 0, 0);
}
#define WAITV0() asm volatile("s_waitcnt vmcnt(0)" ::: "memory")
#define BAR() asm volatile("s_barrier" ::: "memory")

union SMem {
  unsigned char stage[2][4][8192];  // dbuf x {Ahi,Alo,Bhi,Blo} = 64 KB (K-loop)
  float tsp[128][132];              // 67.5 KB transposed C tile (epilogue)
};

__global__ __launch_bounds__(256, 2) void cov_gemm(const unsigned char* __restrict__ pk,
                                                   const float* __restrict__ psum,
                                                   float* __restrict__ out) {
  // XCD-aware: each XCD owns whole batches (per-batch pk = 1MB << 4MB L2)
  const int raw = blockIdx.x;          // 2304 = 36 tile-pairs * 64 batches
  const int xcd = raw & 7;
  const int i = raw >> 3;
  const int n = (i / 36) * 8 + xcd;
  int tp = i % 36;
  int bi = 0;
  while (tp >= 8 - bi) { tp -= 8 - bi; ++bi; }
  const int bj = bi + tp;

  const int t = threadIdx.x;
  const int lane = t & 63;
  const int w = t >> 6;                // 4 waves, 2x2 over the 128x128 tile
  const int wm = w >> 1, wn = w & 1;
  const int fr = lane & 15, g = lane >> 4;

  __shared__ __align__(16) SMem sm;

  f32x4 acc[4][4];
#pragma unroll
  for (int a = 0; a < 4; ++a)
#pragma unroll
    for (int c = 0; c < 4; ++c) acc[a][c] = (f32x4){0.f, 0.f, 0.f, 0.f};

  const size_t baseA = (size_t)((n * 8 + bi) * 8) * 2 * 8192;
  const size_t baseB = (size_t)((n * 8 + bj) * 8) * 2 * 8192;
  const int o = t * 16;

  // fragment LDS byte offsets (same swizzle as pack layout; A/B patterns
  // identical so any k-slot permutation cancels between operands)
  int offA[4], offB[4];
#pragma unroll
  for (int mi = 0; mi < 4; ++mi) {
    const int fa = wm * 64 + mi * 16 + fr;
    offA[mi] = fa * 64 + ((g ^ ((fa >> 1) & 3)) * 16);
    const int fbc = wn * 64 + mi * 16 + fr;
    offB[mi] = fbc * 64 + ((g ^ ((fbc >> 1) & 3)) * 16);
  }

#define STAGE(buf, kb)                                                     \
  do {                                                                     \
    const unsigned char* pA = pk + baseA + (size_t)(kb)*16384;             \
    const unsigned char* pB = pk + baseB + (size_t)(kb)*16384;             \
    gload16(pA + o,         &sm.stage[buf][0][o]);                         \
    gload16(pA + o + 4096,  &sm.stage[buf][0][o + 4096]);                  \
    gload16(pA + 8192 + o,  &sm.stage[buf][1][o]);                         \
    gload16(pA + 12288 + o, &sm.stage[buf][1][o + 4096]);                  \
    gload16(pB + o,         &sm.stage[buf][2][o]);                         \
    gload16(pB + o + 4096,  &sm.stage[buf][2][o + 4096]);                  \
    gload16(pB + 8192 + o,  &sm.stage[buf][3][o]);                         \
    gload16(pB + 12288 + o, &sm.stage[buf][3][o + 4096]);                  \
  } while (0)

  STAGE(0, 0);
  WAITV0();
  BAR();

  for (int kb = 0; kb < 8; ++kb) {
    const int cur = kb & 1;
    if (kb < 7) STAGE(cur ^ 1, kb + 1);  // prefetch flies under this iter's MFMA

    s16x8 ah[4], al[4], bh[4], bl[4];
#pragma unroll
    for (int mi = 0; mi < 4; ++mi) {
      ah[mi] = *reinterpret_cast<const s16x8*>(&sm.stage[cur][0][offA[mi]]);
      al[mi] = *reinterpret_cast<const s16x8*>(&sm.stage[cur][1][offA[mi]]);
    }
#pragma unroll
    for (int nj = 0; nj < 4; ++nj) {
      bh[nj] = *reinterpret_cast<const s16x8*>(&sm.stage[cur][2][offB[nj]]);
      bl[nj] = *reinterpret_cast<const s16x8*>(&sm.stage[cur][3][offB[nj]]);
    }
#pragma unroll
    for (int mi = 0; mi < 4; ++mi)
#pragma unroll
      for (int nj = 0; nj < 4; ++nj) {
        // S ~= hi*hi + hi*lo + lo*hi  (drop lo*lo: ~2^-16 rel)
        acc[mi][nj] = __builtin_amdgcn_mfma_f32_16x16x32_bf16(ah[mi], bh[nj], acc[mi][nj], 0, 0, 0);
        acc[mi][nj] = __builtin_amdgcn_mfma_f32_16x16x32_bf16(ah[mi], bl[nj], acc[mi][nj], 0, 0, 0);
        acc[mi][nj] = __builtin_amdgcn_mfma_f32_16x16x32_bf16(al[mi], bh[nj], acc[mi][nj], 0, 0, 0);
      }

    if (kb < 7) {
      WAITV0();  // next-tile loads complete (covered by MFMA)
      BAR();     // all waves done reading buf[cur] -> safe to overwrite
    }
  }
#undef STAGE

  // epilogue: mean correction (su from psum partials, L2-hit) + eps*I
  const float* pn = psum + (size_t)n * 4096;
  float sd[4];
#pragma unroll
  for (int nj = 0; nj < 4; ++nj) {
    const int c = bj * 128 + wn * 64 + nj * 16 + fr;
    sd[nj] = pn[c] + pn[1024 + c] + pn[2048 + c] + pn[3072 + c];
  }
  float sr_[4][4];
#pragma unroll
  for (int mi = 0; mi < 4; ++mi)
#pragma unroll
    for (int j = 0; j < 4; ++j) {
      const int r = bi * 128 + wm * 64 + mi * 16 + g * 4 + j;
      sr_[mi][j] = pn[r] + pn[1024 + r] + pn[2048 + r] + pn[3072 + r];
    }

  float* outn = out + (size_t)n * (1024 * 1024);
  const bool mir = (bi != bj);  // block-uniform
  if (mir) __syncthreads();     // all waves done with LDS frag reads; stage becomes tsp

#pragma unroll
  for (int mi = 0; mi < 4; ++mi) {
    const int rbase = bi * 128 + wm * 64 + mi * 16 + g * 4;
#pragma unroll
    for (int nj = 0; nj < 4; ++nj) {
      const int cl = wn * 64 + nj * 16 + fr;  // local col in the 128x128 tile
      const int d = bj * 128 + cl;
      f32x4 vv;
#pragma unroll
      for (int j = 0; j < 4; ++j) {
        const int r = rbase + j;
        // C/D mapping (m89): col = lane&15, row = (lane>>4)*4 + j
        float v = (acc[mi][nj][j] - sr_[mi][j] * sd[nj] * (1.f / 256.f)) * (1.f / 255.f);
        if (r == d) v += EPSV;
        vv[j] = v;
        __builtin_nontemporal_store(v, &outn[(size_t)r * 1024 + d]);  // coalesced over fr
      }
      if (mir)  // transposed stage: scatter is cheap in LDS (ds_write_b128)
        *reinterpret_cast<f32x4*>(&sm.tsp[cl][wm * 64 + mi * 16 + g * 4]) = vv;
    }
  }

  if (mir) {  // flush transposed tile with coalesced float4 nt stores
    __syncthreads();
    const int rowt = t >> 5, colw = (t & 31) * 4;
#pragma unroll
    for (int p = 0; p < 16; ++p) {
      const int c = p * 8 + rowt;  // local col = global row (bj*128+c) of mirror
      const f32x4 vv = *reinterpret_cast<const f32x4*>(&sm.tsp[c][colw]);
      __builtin_nontemporal_store(
          vv, reinterpret_cast<f32x4*>(&outn[(size_t)(bj * 128 + c) * 1024 + bi * 128 + colw]));
    }
  }
}

// ---------------- fallback (workspace too small): direct fp32 ----------------
__global__ __launch_bounds__(256) void cov_naive(const float* __restrict__ x,
                                                 float* __restrict__ out) {
  const size_t idx = (size_t)blockIdx.x * 256 + threadIdx.x;
  const int d = (int)(idx & 1023);
  const int c = (int)((idx >> 10) & 1023);
  const int n = (int)(idx >> 20);
  const float* xp = x + (size_t)n * (256 * 1024);
  float scd = 0.f, sc = 0.f, sdd = 0.f;
  for (int s = 0; s < 256; ++s) {
    const float a = xp[(size_t)s * 1024 + c];
    const float bq = xp[(size_t)s * 1024 + d];
    scd += a * bq;
    sc += a;
    sdd += bq;
  }
  float v = (scd - sc * sdd * (1.f / 256.f)) * (1.f / 255.f);
  if (c == d) v += EPSV;
  out[idx] = v;
}

extern "C" void kernel_launch(void* const* d_in, const int* in_sizes, int n_in,
                              void* d_out, int out_size, void* d_ws, size_t ws_size,
                              hipStream_t stream) {
  const float* x = (const float*)d_in[0];
  float* out = (float*)d_out;
  const size_t PK_BYTES = (size_t)64 * 8 * 8 * 2 * 8192;  // 67,108,864
  const size_t PSUM_BYTES = (size_t)64 * 4 * 1024 * 4;    // 1 MB
  if (ws_size >= PK_BYTES + PSUM_BYTES) {
    unsigned char* pk = (unsigned char*)d_ws;
    float* psum = (float*)((unsigned char*)d_ws + PK_BYTES);
    hipLaunchKernelGGL(pack_kernel, dim3(2048), dim3(256), 0, stream, x, pk, psum);
    hipLaunchKernelGGL(cov_gemm, dim3(2304), dim3(256), 0, stream, pk, psum, out);
  } else {
    hipLaunchKernelGGL(cov_naive, dim3(262144), dim3(256), 0, stream, x, out);
  }
}